// Round 7
// baseline (84.723 us; speedup 1.0000x reference)
//
#include <hip/hip_runtime.h>
#include <hip/hip_bf16.h>
#include <stdint.h>

// ---------- helpers ----------
typedef __attribute__((ext_vector_type(8))) __bf16 bf16x8;
typedef __attribute__((ext_vector_type(8))) unsigned short u16x8;
typedef __attribute__((ext_vector_type(4))) float f32x4;

__device__ inline float bf2f(unsigned short u) {
  union { unsigned u; float f; } z; z.u = ((unsigned)u) << 16; return z.f;
}
__device__ inline unsigned short f2bf(float f) {
  union { float f; unsigned u; } z; z.f = f;
  unsigned r = z.u + 0x7fffu + ((z.u >> 16) & 1u);
  return (unsigned short)(r >> 16);
}
__device__ inline void gload_lds16(const void* g, void* l) {
  __builtin_amdgcn_global_load_lds((const __attribute__((address_space(1))) void*)g,
                                   (__attribute__((address_space(3))) void*)l, 16, 0, 0);
}

// ---------- fused q/k/v projection (f32 A and W, inline cvt) + weight conversions ----------
// grid (128, 7): by 0-1 -> q (A=x), 2-3 -> k, 4-5 -> v (A=mem); by==6 -> convert Wo/We/Ws/rpe.
__global__ __launch_bounds__(256, 2) void gemm_proj(
    const float* __restrict__ x, const float* __restrict__ mem,
    const float* __restrict__ Wq, const float* __restrict__ Wk, const float* __restrict__ Wv,
    const float* __restrict__ Wo, const float* __restrict__ We, const float* __restrict__ Ws,
    const float* __restrict__ Wrpe, const float* __restrict__ brpe,
    const float* __restrict__ bq, const float* __restrict__ bk, const float* __restrict__ bv,
    unsigned short* __restrict__ qbuf, unsigned short* __restrict__ kbp,
    unsigned short* __restrict__ vbp,
    unsigned short* __restrict__ wob, unsigned short* __restrict__ web,
    unsigned short* __restrict__ wsb, float4* __restrict__ rpe4) {
  const int tid = threadIdx.x;
  const int by = blockIdx.y;
  const long bm = blockIdx.x;

  if (by == 6) {
#pragma unroll
    for (int it = 0; it < 3; ++it) {
      const int j = (int)bm + 128 * it;
      if (j < 64) {
        const float4 v = *(const float4*)(Wo + (long)j * 1024 + tid * 4);
        ushort4 o; o.x = f2bf(v.x); o.y = f2bf(v.y); o.z = f2bf(v.z); o.w = f2bf(v.w);
        *(ushort4*)(wob + (long)j * 1024 + tid * 4) = o;
      } else if (j < 192) {
        const float4 v = *(const float4*)(We + (long)(j - 64) * 1024 + tid * 4);
        ushort4 o; o.x = f2bf(v.x); o.y = f2bf(v.y); o.z = f2bf(v.z); o.w = f2bf(v.w);
        *(ushort4*)(web + (long)(j - 64) * 1024 + tid * 4) = o;
      } else if (j < 320) {
        const float4 v = *(const float4*)(Ws + (long)(j - 192) * 1024 + tid * 4);
        ushort4 o; o.x = f2bf(v.x); o.y = f2bf(v.y); o.z = f2bf(v.z); o.w = f2bf(v.w);
        *(ushort4*)(wsb + (long)(j - 192) * 1024 + tid * 4) = o;
      } else if (j == 320) {
        if (tid < 128) {
          float4 r;
          r.x = Wrpe[3 * tid]; r.y = Wrpe[3 * tid + 1]; r.z = Wrpe[3 * tid + 2]; r.w = brpe[tid];
          rpe4[tid] = r;
        }
      }
    }
    return;
  }

  __shared__ __attribute__((aligned(16))) char lds[4096 + 8192];  // A 4KB | B 8KB (bf16)
  const int lane = tid & 63;
  const int wm = tid >> 7, wo = (tid >> 6) & 1;

  const float* Ab; const float* Wf; const float* biasp; unsigned short* outp; int cb;
  if (by < 2)      { Ab = x;   Wf = Wq + (long)by * 128 * 256;       biasp = bq + by * 128;       outp = qbuf; cb = by * 128; }
  else if (by < 4) { Ab = mem; Wf = Wk + (long)(by - 2) * 128 * 256; biasp = bk + (by - 2) * 128; outp = kbp;  cb = (by - 2) * 128; }
  else             { Ab = mem; Wf = Wv + (long)(by - 4) * 128 * 256; biasp = bv + (by - 4) * 128; outp = vbp;  cb = (by - 4) * 128; }

  f32x4 acc[2][4] = {};
  for (int kt = 0; kt < 8; ++kt) {
#pragma unroll
    for (int c = 0; c < 2; ++c) {
      const int fb = c * 4096 + tid * 16;
      const int row = fb >> 7, colb = fb & 127;
      const float4 a4 = *(const float4*)((const char*)Ab + (bm * 64 + row) * 1024 + kt * 128 + colb);
      ushort4 o; o.x = f2bf(a4.x); o.y = f2bf(a4.y); o.z = f2bf(a4.z); o.w = f2bf(a4.w);
      *(ushort4*)(lds + row * 64 + (colb >> 1)) = o;
    }
#pragma unroll
    for (int c = 0; c < 4; ++c) {
      const int fb = c * 4096 + tid * 16;
      const int row = fb >> 7, colb = fb & 127;
      const float4 a4 = *(const float4*)((const char*)Wf + (long)row * 1024 + kt * 128 + colb);
      ushort4 o; o.x = f2bf(a4.x); o.y = f2bf(a4.y); o.z = f2bf(a4.z); o.w = f2bf(a4.w);
      *(ushort4*)(lds + 4096 + row * 64 + (colb >> 1)) = o;
    }
    __syncthreads();
    bf16x8 af[2], bfr[4];
    const int kb = (lane >> 4) * 16;
#pragma unroll
    for (int i = 0; i < 2; ++i)
      af[i] = *(const bf16x8*)(lds + (wm * 32 + i * 16 + (lane & 15)) * 64 + kb);
#pragma unroll
    for (int j = 0; j < 4; ++j)
      bfr[j] = *(const bf16x8*)(lds + 4096 + (wo * 64 + j * 16 + (lane & 15)) * 64 + kb);
#pragma unroll
    for (int i = 0; i < 2; ++i)
#pragma unroll
      for (int j = 0; j < 4; ++j)
        acc[i][j] = __builtin_amdgcn_mfma_f32_16x16x32_bf16(af[i], bfr[j], acc[i][j], 0, 0, 0);
    __syncthreads();
  }

#pragma unroll
  for (int i = 0; i < 2; ++i) {
#pragma unroll
    for (int j = 0; j < 4; ++j) {
      const int lc = wo * 64 + j * 16 + (lane & 15);
      const float bvv = biasp[lc];
#pragma unroll
      for (int r = 0; r < 4; ++r) {
        const long rowg = bm * 64 + wm * 32 + i * 16 + (lane >> 4) * 4 + r;
        outp[rowg * 256 + cb + lc] = f2bf(acc[i][j][r] + bvv);
      }
    }
  }
}

// ---------- fused gather + RPE rotary + MHA, register-resident K/q ----------
__global__ __launch_bounds__(256, 4) void attn2(
    const unsigned short* __restrict__ qb,   // N x 256 (bf16)
    const unsigned short* __restrict__ kbp,  // M x 256 (bf16)
    const unsigned short* __restrict__ vbp,  // M x 256 (bf16)
    const int* __restrict__ idx,             // N x 32
    const float* __restrict__ icoord,        // N x 3
    const float* __restrict__ mcoord,        // M x 3
    const float* __restrict__ mask,          // N x 32
    const float4* __restrict__ rpe4,         // 128 x {w0,w1,w2,b}
    unsigned short* __restrict__ hb)         // N x 256 (bf16)
{
  __shared__ int idx_s[32];
  __shared__ float4 relm_s[32];
  __shared__ float4 rpe_s[128];
  __shared__ float p_s[256];
  __shared__ __attribute__((aligned(16))) unsigned short vls[32][256];

  const int n = blockIdx.x, t = threadIdx.x;
  if (t < 128) rpe_s[t] = rpe4[t];
  if (t < 32) {
    const int m = idx[n * 32 + t];
    idx_s[t] = m;
    float4 rm;
    rm.x = mcoord[(long)m * 3 + 0] - icoord[(long)n * 3 + 0];
    rm.y = mcoord[(long)m * 3 + 1] - icoord[(long)n * 3 + 1];
    rm.z = mcoord[(long)m * 3 + 2] - icoord[(long)n * 3 + 2];
    rm.w = mask[n * 32 + t];
    relm_s[t] = rm;
  }
  __syncthreads();

#pragma unroll
  for (int i = 0; i < 4; ++i) {
    const int b = i * 4096 + t * 16;
    const int r = b >> 9, cb = b & 511;
    gload_lds16((const char*)vbp + (long)idx_s[r] * 512 + cb, (char*)vls + b);
  }

  const int h = t >> 5, k = t & 31;
  const float4 rm = relm_s[k];
  const long krow = idx_s[k];

  u16x8 kv8[4], qv8[4];
  {
    const u16x8* kp = (const u16x8*)(kbp + krow * 256 + h * 32);
    const u16x8* qp = (const u16x8*)(qb + (long)n * 256 + h * 32);
#pragma unroll
    for (int i = 0; i < 4; ++i) { kv8[i] = kp[i]; qv8[i] = qp[i]; }
  }

  float sc = 0.f;
#pragma unroll
  for (int j2 = 0; j2 < 16; ++j2) {
    const float4 wj = rpe_s[h * 16 + j2];
    const float ang = fmaf(wj.x, rm.x, fmaf(wj.y, rm.y, fmaf(wj.z, rm.z, wj.w)));
    float sn, cs;
    __sincosf(ang, &sn, &cs);
    const int wi = j2 >> 2, e0 = (j2 & 3) * 2;
    const float x0 = bf2f(kv8[wi][e0]), x1 = bf2f(kv8[wi][e0 + 1]);
    const float q0 = bf2f(qv8[wi][e0]), q1 = bf2f(qv8[wi][e0 + 1]);
    const float k0 = fmaf(x0, cs, -x1 * sn);
    const float k1 = fmaf(x0, sn, x1 * cs);
    sc = fmaf(q0, k0, sc);
    sc = fmaf(q1, k1, sc);
  }
  sc = sc * 0.17677669529663687f - 1e6f * (1.f - rm.w);

  float mx = sc;
#pragma unroll
  for (int m = 16; m > 0; m >>= 1) mx = fmaxf(mx, __shfl_xor(mx, m, 32));
  const float e = __expf(sc - mx);
  float sum = e;
#pragma unroll
  for (int m = 16; m > 0; m >>= 1) sum += __shfl_xor(sum, m, 32);
  p_s[t] = e / sum;
  __syncthreads();

  float acc = 0.f;
#pragma unroll
  for (int k4 = 0; k4 < 8; ++k4) {
    const float4 p4 = *(const float4*)(p_s + (t >> 5) * 32 + k4 * 4);
    acc = fmaf(p4.x, bf2f(vls[k4 * 4 + 0][t]), acc);
    acc = fmaf(p4.y, bf2f(vls[k4 * 4 + 1][t]), acc);
    acc = fmaf(p4.z, bf2f(vls[k4 * 4 + 2][t]), acc);
    acc = fmaf(p4.w, bf2f(vls[k4 * 4 + 3][t]), acc);
  }
  hb[(long)n * 256 + t] = f2bf(acc);
}

// ---------- mega-tail: o-proj + res + LN1 + FFN1(relu) + FFN2 + res + LN2 ----------
// BM=32 rows/block, grid 256, 256 threads (4 waves, each owns a 64-col stripe).
// LDS 64KB: out1[0,16K) | A/ff[16K,48K) | wtile[48K,64K) (part[] aliases wtile during LN).
__global__ __launch_bounds__(256) void megatail(
    const unsigned short* __restrict__ hb, const float* __restrict__ x,
    const unsigned short* __restrict__ wob, const unsigned short* __restrict__ web,
    const unsigned short* __restrict__ wsb,
    const float* __restrict__ bo, const float* __restrict__ g1, const float* __restrict__ b1,
    const float* __restrict__ be, const float* __restrict__ bs,
    const float* __restrict__ g2, const float* __restrict__ b2,
    float* __restrict__ outf) {
  __shared__ __attribute__((aligned(16))) char lds[65536];
  char* const out1_l = lds;                  // [32][512B] bf16 (LN1 output)
  char* const ffa_l  = lds + 16384;          // stage1 A [32][512B]; then ff [32][1024B]
  char* const wt_l   = lds + 49152;          // [256][64B] streamed W tile
  float2* const part = (float2*)(lds + 49152);  // aliases wt_l, used only when wt idle

  const int tid = threadIdx.x, lane = tid & 63;
  const int wv = tid >> 6;
  const long bm = blockIdx.x;
  const int kb = (lane >> 4) * 16;
  const int lrow = (lane >> 4) * 4;
  const int c15 = lane & 15;
  int colg[4];
#pragma unroll
  for (int j = 0; j < 4; ++j) colg[j] = wv * 64 + j * 16 + c15;

  f32x4 acc[2][4];

  // ---- stage1 A: hb rows -> LDS ----
#pragma unroll
  for (int p = 0; p < 4; ++p) {
    const int b = p * 4096 + tid * 16;
    gload_lds16((const char*)hb + (bm * 32 + (b >> 9)) * 512 + (b & 511), ffa_l + b);
  }
#pragma unroll
  for (int i = 0; i < 2; ++i)
#pragma unroll
    for (int j = 0; j < 4; ++j) acc[i][j] = (f32x4){0.f, 0.f, 0.f, 0.f};

  // ---- stage1 K-loop: out1 = hb @ Wo^T ----
  for (int kt = 0; kt < 8; ++kt) {
#pragma unroll
    for (int c = 0; c < 4; ++c) {
      const int b = c * 4096 + tid * 16;
      gload_lds16((const char*)wob + (long)(b >> 6) * 512 + kt * 64 + (b & 63), wt_l + b);
    }
    __syncthreads();
    bf16x8 af[2], bfq[4];
#pragma unroll
    for (int i = 0; i < 2; ++i)
      af[i] = *(const bf16x8*)(ffa_l + (i * 16 + c15) * 512 + kt * 64 + kb);
#pragma unroll
    for (int j = 0; j < 4; ++j)
      bfq[j] = *(const bf16x8*)(wt_l + (wv * 64 + j * 16 + c15) * 64 + kb);
#pragma unroll
    for (int i = 0; i < 2; ++i)
#pragma unroll
      for (int j = 0; j < 4; ++j)
        acc[i][j] = __builtin_amdgcn_mfma_f32_16x16x32_bf16(af[i], bfq[j], acc[i][j], 0, 0, 0);
    __syncthreads();
  }

  // ---- epilogue 1: + bo + x, LN1 -> out1_l (bf16) ----
#pragma unroll
  for (int i = 0; i < 2; ++i)
#pragma unroll
    for (int r = 0; r < 4; ++r) {
      const int rl = i * 16 + lrow + r;
      const long rowg = bm * 32 + rl;
#pragma unroll
      for (int j = 0; j < 4; ++j)
        acc[i][j][r] += bo[colg[j]] + x[rowg * 256 + colg[j]];
    }
#pragma unroll
  for (int i = 0; i < 2; ++i)
#pragma unroll
    for (int r = 0; r < 4; ++r) {
      const int rl = i * 16 + lrow + r;
      float s = 0.f, s2 = 0.f;
#pragma unroll
      for (int j = 0; j < 4; ++j) { const float v = acc[i][j][r]; s += v; s2 = fmaf(v, v, s2); }
#pragma unroll
      for (int m = 8; m > 0; m >>= 1) { s += __shfl_xor(s, m, 16); s2 += __shfl_xor(s2, m, 16); }
      if (c15 == 0) part[wv * 32 + rl] = make_float2(s, s2);
    }
  __syncthreads();
#pragma unroll
  for (int i = 0; i < 2; ++i)
#pragma unroll
    for (int r = 0; r < 4; ++r) {
      const int rl = i * 16 + lrow + r;
      float s = 0.f, s2 = 0.f;
#pragma unroll
      for (int q = 0; q < 4; ++q) { s += part[q * 32 + rl].x; s2 += part[q * 32 + rl].y; }
      const float mu = s * (1.f / 256.f);
      const float var = s2 * (1.f / 256.f) - mu * mu;
      const float inv = rsqrtf(var + 1e-5f);
#pragma unroll
      for (int j = 0; j < 4; ++j) {
        const float y = (acc[i][j][r] - mu) * inv * g1[colg[j]] + b1[colg[j]];
        *(unsigned short*)(out1_l + rl * 512 + colg[j] * 2) = f2bf(y);
      }
    }
  __syncthreads();  // out1 visible; part reads done before wt reuse

  // ---- stage2: ff = relu(out1 @ We^T + be), two 256-col halves ----
  for (int hc = 0; hc < 2; ++hc) {
#pragma unroll
    for (int i = 0; i < 2; ++i)
#pragma unroll
      for (int j = 0; j < 4; ++j) acc[i][j] = (f32x4){0.f, 0.f, 0.f, 0.f};
    for (int kt = 0; kt < 8; ++kt) {
#pragma unroll
      for (int c = 0; c < 4; ++c) {
        const int b = c * 4096 + tid * 16;
        gload_lds16((const char*)web + ((long)hc * 256 + (b >> 6)) * 512 + kt * 64 + (b & 63), wt_l + b);
      }
      __syncthreads();
      bf16x8 af[2], bfq[4];
#pragma unroll
      for (int i = 0; i < 2; ++i)
        af[i] = *(const bf16x8*)(out1_l + (i * 16 + c15) * 512 + kt * 64 + kb);
#pragma unroll
      for (int j = 0; j < 4; ++j)
        bfq[j] = *(const bf16x8*)(wt_l + (wv * 64 + j * 16 + c15) * 64 + kb);
#pragma unroll
      for (int i = 0; i < 2; ++i)
#pragma unroll
        for (int j = 0; j < 4; ++j)
          acc[i][j] = __builtin_amdgcn_mfma_f32_16x16x32_bf16(af[i], bfq[j], acc[i][j], 0, 0, 0);
      __syncthreads();
    }
#pragma unroll
    for (int i = 0; i < 2; ++i)
#pragma unroll
      for (int r = 0; r < 4; ++r) {
        const int rl = i * 16 + lrow + r;
#pragma unroll
        for (int j = 0; j < 4; ++j) {
          const int col = hc * 256 + colg[j];
          const float v = acc[i][j][r] + be[col];
          *(unsigned short*)(ffa_l + rl * 1024 + col * 2) = f2bf(v > 0.f ? v : 0.f);
        }
      }
  }

  // ---- stage3: out = LN2(out1 + ff @ Ws^T + bs) ----
#pragma unroll
  for (int i = 0; i < 2; ++i)
#pragma unroll
    for (int j = 0; j < 4; ++j) acc[i][j] = (f32x4){0.f, 0.f, 0.f, 0.f};
  for (int kt = 0; kt < 16; ++kt) {
#pragma unroll
    for (int c = 0; c < 4; ++c) {
      const int b = c * 4096 + tid * 16;
      gload_lds16((const char*)wsb + (long)(b >> 6) * 1024 + kt * 64 + (b & 63), wt_l + b);
    }
    __syncthreads();
    bf16x8 af[2], bfq[4];
#pragma unroll
    for (int i = 0; i < 2; ++i)
      af[i] = *(const bf16x8*)(ffa_l + (i * 16 + c15) * 1024 + kt * 64 + kb);
#pragma unroll
    for (int j = 0; j < 4; ++j)
      bfq[j] = *(const bf16x8*)(wt_l + (wv * 64 + j * 16 + c15) * 64 + kb);
#pragma unroll
    for (int i = 0; i < 2; ++i)
#pragma unroll
      for (int j = 0; j < 4; ++j)
        acc[i][j] = __builtin_amdgcn_mfma_f32_16x16x32_bf16(af[i], bfq[j], acc[i][j], 0, 0, 0);
    __syncthreads();
  }
#pragma unroll
  for (int i = 0; i < 2; ++i)
#pragma unroll
    for (int r = 0; r < 4; ++r) {
      const int rl = i * 16 + lrow + r;
#pragma unroll
      for (int j = 0; j < 4; ++j)
        acc[i][j][r] += bs[colg[j]] + bf2f(*(const unsigned short*)(out1_l + rl * 512 + colg[j] * 2));
    }
#pragma unroll
  for (int i = 0; i < 2; ++i)
#pragma unroll
    for (int r = 0; r < 4; ++r) {
      const int rl = i * 16 + lrow + r;
      float s = 0.f, s2 = 0.f;
#pragma unroll
      for (int j = 0; j < 4; ++j) { const float v = acc[i][j][r]; s += v; s2 = fmaf(v, v, s2); }
#pragma unroll
      for (int m = 8; m > 0; m >>= 1) { s += __shfl_xor(s, m, 16); s2 += __shfl_xor(s2, m, 16); }
      if (c15 == 0) part[wv * 32 + rl] = make_float2(s, s2);
    }
  __syncthreads();
#pragma unroll
  for (int i = 0; i < 2; ++i)
#pragma unroll
    for (int r = 0; r < 4; ++r) {
      const int rl = i * 16 + lrow + r;
      const long rowg = bm * 32 + rl;
      float s = 0.f, s2 = 0.f;
#pragma unroll
      for (int q = 0; q < 4; ++q) { s += part[q * 32 + rl].x; s2 += part[q * 32 + rl].y; }
      const float mu = s * (1.f / 256.f);
      const float var = s2 * (1.f / 256.f) - mu * mu;
      const float inv = rsqrtf(var + 1e-5f);
#pragma unroll
      for (int j = 0; j < 4; ++j)
        outf[rowg * 256 + colg[j]] = (acc[i][j][r] - mu) * inv * g2[colg[j]] + b2[colg[j]];
    }
}

// ---------- launch ----------
extern "C" void kernel_launch(void* const* d_in, const int* in_sizes, int n_in,
                              void* d_out, int out_size, void* d_ws, size_t ws_size,
                              hipStream_t stream) {
  const float* x    = (const float*)d_in[0];
  const float* mem  = (const float*)d_in[1];
  const int* idx    = (const int*)d_in[2];
  const float* ic   = (const float*)d_in[3];
  const float* mc   = (const float*)d_in[4];
  const float* mask = (const float*)d_in[5];
  const float* Wq = (const float*)d_in[6];  const float* bq = (const float*)d_in[7];
  const float* Wk = (const float*)d_in[8];  const float* bk = (const float*)d_in[9];
  const float* Wv = (const float*)d_in[10]; const float* bv = (const float*)d_in[11];
  const float* Wo = (const float*)d_in[12]; const float* bo = (const float*)d_in[13];
  const float* g1 = (const float*)d_in[14]; const float* b1 = (const float*)d_in[15];
  const float* Wrpe = (const float*)d_in[16]; const float* brpe = (const float*)d_in[17];
  const float* We = (const float*)d_in[18]; const float* be = (const float*)d_in[19];
  const float* Ws = (const float*)d_in[20]; const float* bs = (const float*)d_in[21];
  const float* g2 = (const float*)d_in[22]; const float* b2 = (const float*)d_in[23];

  char* w = (char*)d_ws;
  const size_t MB = 1ull << 20;
  unsigned short* kbp  = (unsigned short*)(w + 0);        // 4MB
  unsigned short* vbp  = (unsigned short*)(w + 4 * MB);   // 4MB
  unsigned short* qbuf = (unsigned short*)(w + 8 * MB);   // 4MB
  unsigned short* hb   = (unsigned short*)(w + 12 * MB);  // 4MB
  unsigned short* wob  = (unsigned short*)(w + 16 * MB);  // 128KB
  unsigned short* web  = wob + 65536;                     // 256KB
  unsigned short* wsb  = web + 131072;                    // 256KB
  float4*         rpe4 = (float4*)(wsb + 131072);         // 2KB

  // fused q/k/v projections + weight conversions (one launch)
  gemm_proj<<<dim3(128, 7), 256, 0, stream>>>(
      x, mem, Wq, Wk, Wv, Wo, We, Ws, Wrpe, brpe, bq, bk, bv,
      qbuf, kbp, vbp, wob, web, wsb, rpe4);

  // fused gather + rotary + attention
  attn2<<<8192, 256, 0, stream>>>(qbuf, kbp, vbp, idx, ic, mc, mask, rpe4, hb);

  // entire tail in one kernel
  megatail<<<256, 256, 0, stream>>>(hb, x, wob, web, wsb,
                                    bo, g1, b1, be, bs, g2, b2, (float*)d_out);
}